// Round 6
// baseline (466.987 us; speedup 1.0000x reference)
//
#include <hip/hip_runtime.h>

#define N_NODES 50000
#define N_EDGES 800000
#define N_EL    200000
#define CH      128
#define NTILES  3125   // 50000/16

typedef __attribute__((ext_vector_type(8))) short bf16x8;
typedef __attribute__((ext_vector_type(4))) float f32x4;

__device__ __forceinline__ unsigned short f2bf(float f){
  unsigned int u = __float_as_uint(f);
  unsigned int r = (u + 0x7fff + ((u >> 16) & 1)) >> 16;
  return (unsigned short)r;
}
__device__ __forceinline__ float bflo(unsigned int v){ return __uint_as_float(v << 16); }
__device__ __forceinline__ float bfhi(unsigned int v){ return __uint_as_float(v & 0xffff0000u); }
__device__ __forceinline__ float bf2f(unsigned short u){ return __uint_as_float(((unsigned int)u) << 16); }

// ---------------- degree histogram --------------------------------------------
__global__ void hist_kernel(const int* __restrict__ ei, int* deg, int* cnt){
  int i = blockIdx.x*blockDim.x + threadIdx.x;
  if (i < N_EDGES){
    atomicAdd(&deg[ei[i]], 1);
    atomicAdd(&cnt[ei[N_EDGES + i]], 1);
  }
}

__global__ void dinv_kernel(const int* __restrict__ deg, float* __restrict__ dinv){
  int i = blockIdx.x*blockDim.x + threadIdx.x;
  if (i < N_NODES){
    int d = deg[i];
    dinv[i] = d > 0 ? rsqrtf((float)d) : 0.0f;
  }
}

// ---------------- hierarchical exclusive scan ---------------------------------
#define SCAN_NB 196   // ceil(50000/256)

__global__ void scan_bsum(const int* __restrict__ cnt, int* __restrict__ bsum){
  __shared__ int sh[256];
  int i = blockIdx.x*256 + threadIdx.x;
  sh[threadIdx.x] = (i < N_NODES) ? cnt[i] : 0;
  __syncthreads();
  for (int off = 128; off >= 1; off >>= 1){
    if ((int)threadIdx.x < off) sh[threadIdx.x] += sh[threadIdx.x + off];
    __syncthreads();
  }
  if (threadIdx.x == 0) bsum[blockIdx.x] = sh[0];
}

__global__ void scan_boff(const int* __restrict__ bsum, int* __restrict__ boff){
  __shared__ int sh[256];
  int t = threadIdx.x;
  int v = (t < SCAN_NB) ? bsum[t] : 0;
  sh[t] = v;
  __syncthreads();
  for (int off = 1; off < 256; off <<= 1){
    int tv = (t >= off) ? sh[t - off] : 0;
    __syncthreads();
    sh[t] += tv;
    __syncthreads();
  }
  if (t < SCAN_NB) boff[t] = sh[t] - v;
}

__global__ void scan_final(const int* __restrict__ cnt, const int* __restrict__ boff,
                           int* __restrict__ rowoff, int* __restrict__ cursor){
  __shared__ int sh[256];
  int t = threadIdx.x;
  int i = blockIdx.x*256 + t;
  int v = (i < N_NODES) ? cnt[i] : 0;
  sh[t] = v;
  __syncthreads();
  for (int off = 1; off < 256; off <<= 1){
    int tv = (t >= off) ? sh[t - off] : 0;
    __syncthreads();
    sh[t] += tv;
    __syncthreads();
  }
  int o = boff[blockIdx.x] + sh[t] - v;
  if (i < N_NODES){ rowoff[i] = o; cursor[i] = o; }
  if (i == N_NODES - 1) rowoff[N_NODES] = N_EDGES;
}

__global__ void scatter_kernel(const int* __restrict__ ei, const float* __restrict__ dinv,
                               int* cursor, int* __restrict__ csr_src,
                               float* __restrict__ csr_norm){
  int i = blockIdx.x*blockDim.x + threadIdx.x;
  if (i < N_EDGES){
    int s = ei[i];
    int d = ei[N_EDGES + i];
    int pos = atomicAdd(&cursor[d], 1);
    csr_src[pos]  = s;
    csr_norm[pos] = -(dinv[s] * dinv[d]);
  }
}

// ---------------- converts ----------------------------------------------------
// xH[node][0..127]=bf16(x row), [128..255]=bf16(H row)
__global__ void cvt_xH(const float* __restrict__ x, const float* __restrict__ H,
                       unsigned short* __restrict__ xH){
  const int Q = (N_NODES*CH)/4;
  int i = blockIdx.x*blockDim.x + threadIdx.x;
  if (i >= 2*Q) return;
  const float* src = (i < Q) ? x : H;
  int off = (i < Q) ? i : i - Q;
  float4 v = ((const float4*)src)[off];
  int node = off >> 5, cg = off & 31;
  uint2 o;
  o.x = (unsigned int)f2bf(v.x) | ((unsigned int)f2bf(v.y) << 16);
  o.y = (unsigned int)f2bf(v.z) | ((unsigned int)f2bf(v.w) << 16);
  *(uint2*)(xH + (size_t)node*256 + ((i < Q) ? 0 : 128) + cg*4) = o;
}

// wt[m][col][k] = W_t[g][k][col], m = t*3+g, t in {Wx0,Wx1,Wh0,Wh1}
__global__ void cvt_w(const float* __restrict__ Wx0, const float* __restrict__ Wx1,
                      const float* __restrict__ Wh0, const float* __restrict__ Wh1,
                      unsigned short* __restrict__ wt){
  int i = blockIdx.x*blockDim.x + threadIdx.x;
  if (i >= 12*128*128) return;
  int m = i >> 14;
  int r = i & 16383;
  int col = r >> 7, k = r & 127;
  const float* W[4] = {Wx0, Wx1, Wh0, Wh1};
  const float* src = W[m/3] + (m%3)*16384;
  wt[i] = f2bf(src[k*128 + col]);
}

// ---------------- prop over interleaved x|H (one 512B read per edge) ----------
__global__ void prop_x2(const int* __restrict__ rowoff, const int* __restrict__ csr_src,
                        const float* __restrict__ csr_norm,
                        const unsigned short* __restrict__ xH,
                        unsigned short* __restrict__ px, unsigned short* __restrict__ pH){
  int node = blockIdx.x*4 + ((int)threadIdx.x >> 6);
  if (node >= N_NODES) return;
  int lane = threadIdx.x & 63;
  int half = lane >> 5, il = lane & 31;
  const unsigned short* base = xH + half*128 + il*4;
  int beg = rowoff[node], end = rowoff[node+1];
  float a0 = 0.f, a1 = 0.f, a2 = 0.f, a3 = 0.f;
  int k = beg;
  for (; k + 4 <= end; k += 4){
    int s0 = csr_src[k], s1 = csr_src[k+1], s2 = csr_src[k+2], s3 = csr_src[k+3];
    float w0 = csr_norm[k], w1 = csr_norm[k+1], w2 = csr_norm[k+2], w3 = csr_norm[k+3];
    uint2 v0 = *(const uint2*)(base + (size_t)s0*256);
    uint2 v1 = *(const uint2*)(base + (size_t)s1*256);
    uint2 v2 = *(const uint2*)(base + (size_t)s2*256);
    uint2 v3 = *(const uint2*)(base + (size_t)s3*256);
    a0 += w0*bflo(v0.x) + w1*bflo(v1.x) + w2*bflo(v2.x) + w3*bflo(v3.x);
    a1 += w0*bfhi(v0.x) + w1*bfhi(v1.x) + w2*bfhi(v2.x) + w3*bfhi(v3.x);
    a2 += w0*bflo(v0.y) + w1*bflo(v1.y) + w2*bflo(v2.y) + w3*bflo(v3.y);
    a3 += w0*bfhi(v0.y) + w1*bfhi(v1.y) + w2*bfhi(v2.y) + w3*bfhi(v3.y);
  }
  for (; k < end; ++k){
    int s = csr_src[k];
    float w = csr_norm[k];
    uint2 v = *(const uint2*)(base + (size_t)s*256);
    a0 += w*bflo(v.x); a1 += w*bfhi(v.x);
    a2 += w*bflo(v.y); a3 += w*bfhi(v.y);
  }
  uint2 o;
  o.x = (unsigned int)f2bf(a0) | ((unsigned int)f2bf(a1) << 16);
  o.y = (unsigned int)f2bf(a2) | ((unsigned int)f2bf(a3) << 16);
  unsigned short* O = (half ? pH : px) + (size_t)node*CH + il*4;
  *(uint2*)O = o;
}

// ---------------- prop of one matrix (stride-256 input) -----------------------
__global__ void prop_one(const int* __restrict__ rowoff, const int* __restrict__ csr_src,
                         const float* __restrict__ csr_norm,
                         const unsigned short* __restrict__ V, // stride 256
                         unsigned short* __restrict__ O){      // stride 128
  int node = blockIdx.x*4 + ((int)threadIdx.x >> 6);
  if (node >= N_NODES) return;
  int lane = threadIdx.x & 63;
  const unsigned short* base = V + lane*2;
  int beg = rowoff[node], end = rowoff[node+1];
  float a0 = 0.f, a1 = 0.f;
  int k = beg;
  for (; k + 4 <= end; k += 4){
    int s0 = csr_src[k], s1 = csr_src[k+1], s2 = csr_src[k+2], s3 = csr_src[k+3];
    float w0 = csr_norm[k], w1 = csr_norm[k+1], w2 = csr_norm[k+2], w3 = csr_norm[k+3];
    unsigned int v0 = *(const unsigned int*)(base + (size_t)s0*256);
    unsigned int v1 = *(const unsigned int*)(base + (size_t)s1*256);
    unsigned int v2 = *(const unsigned int*)(base + (size_t)s2*256);
    unsigned int v3 = *(const unsigned int*)(base + (size_t)s3*256);
    a0 += w0*bflo(v0) + w1*bflo(v1) + w2*bflo(v2) + w3*bflo(v3);
    a1 += w0*bfhi(v0) + w1*bfhi(v1) + w2*bfhi(v2) + w3*bfhi(v3);
  }
  for (; k < end; ++k){
    int s = csr_src[k];
    float w = csr_norm[k];
    unsigned int v = *(const unsigned int*)(base + (size_t)s*256);
    a0 += w*bflo(v); a1 += w*bfhi(v);
  }
  *(unsigned int*)(O + (size_t)node*CH + lane*2) =
      (unsigned int)f2bf(a0) | ((unsigned int)f2bf(a1) << 16);
}

// ---------------- fused gates Z,R,P2: B stationary in registers ---------------
// 512 thr = 8 waves; wave w owns 16-col stripe [w*16, w*16+16).
// Grid-stride over 3125 row-tiles of 16 rows. No LDS, no barriers.
__launch_bounds__(512, 2)
__global__ void mfma_gates2(unsigned short* xH,
                            const unsigned short* __restrict__ px,
                            const unsigned short* __restrict__ pH,
                            const unsigned short* __restrict__ wt,
                            const float* __restrict__ bx, const float* __restrict__ bh,
                            unsigned short* __restrict__ zb,
                            float* __restrict__ pre2){
  const int M = 128*128;
  int lane = threadIdx.x & 63;
  int w    = threadIdx.x >> 6;
  int lr   = lane & 15;
  int kq   = lane >> 4;
  int mycol = w*16 + lr;

  const unsigned short* Am[4] = {xH, px, xH + 128, pH};
  const int strA[4] = {256, 128, 256, 128};

  // stationary B fragments (all compile-time indexed -> registers)
  bf16x8 BZ[16], BR[16], BP[8];
  #pragma unroll
  for (int t = 0; t < 4; ++t){
    #pragma unroll
    for (int q = 0; q < 4; ++q){
      const unsigned short* base = wt + (size_t)(t*3)*M + (size_t)mycol*CH + q*32 + kq*8;
      BZ[t*4+q] = *(const bf16x8*)(base);
      BR[t*4+q] = *(const bf16x8*)(base + M);
      if (t < 2) BP[t*4+q] = *(const bf16x8*)(base + 2*M);
    }
  }

  float bsZ = bx[mycol]       + bh[mycol];
  float bsR = bx[128 + mycol] + bh[128 + mycol];
  float bsP = bx[256 + mycol];

  for (int tile = blockIdx.x; tile < NTILES; tile += gridDim.x){
    int r0 = tile * 16;
    int rA = r0 + lr;
    f32x4 accZ = (f32x4){0.f,0.f,0.f,0.f};
    f32x4 accR = (f32x4){0.f,0.f,0.f,0.f};
    f32x4 accP = (f32x4){0.f,0.f,0.f,0.f};
    #pragma unroll
    for (int t = 0; t < 4; ++t){
      const unsigned short* Ap = Am[t] + (size_t)rA*strA[t] + kq*8;
      #pragma unroll
      for (int q = 0; q < 4; ++q){
        bf16x8 a = *(const bf16x8*)(Ap + q*32);
        accZ = __builtin_amdgcn_mfma_f32_16x16x32_bf16(a, BZ[t*4+q], accZ, 0, 0, 0);
        accR = __builtin_amdgcn_mfma_f32_16x16x32_bf16(a, BR[t*4+q], accR, 0, 0, 0);
        if (t < 2)
          accP = __builtin_amdgcn_mfma_f32_16x16x32_bf16(a, BP[t*4+q], accP, 0, 0, 0);
      }
    }
    #pragma unroll
    for (int j = 0; j < 4; ++j){
      int row = r0 + kq*4 + j;
      size_t ro = (size_t)row*CH + mycol;
      size_t rh = (size_t)row*256 + 128 + mycol;
      float z = 1.0f/(1.0f + __expf(-(accZ[j] + bsZ)));
      float r = 1.0f/(1.0f + __expf(-(accR[j] + bsR)));
      float h = bf2f(xH[rh]);
      zb[ro]   = f2bf(z);
      xH[rh]   = f2bf(h * r);
      pre2[ro] = accP[j] + bsP;
    }
  }
}

// ---------------- final: gate2 h-part + GRU epilogue (B stationary) -----------
__launch_bounds__(512, 2)
__global__ void mfma_final2(const unsigned short* __restrict__ hr,   // stride 256
                            const unsigned short* __restrict__ phr,  // stride 128
                            const unsigned short* __restrict__ B0,
                            const unsigned short* __restrict__ B1,
                            const float* __restrict__ bias,
                            const float* __restrict__ Hp, const float* __restrict__ pre2,
                            const unsigned short* __restrict__ zb,
                            float* __restrict__ hidden,
                            unsigned short* __restrict__ relu_b){
  int lane = threadIdx.x & 63;
  int w    = threadIdx.x >> 6;
  int lr   = lane & 15;
  int kq   = lane >> 4;
  int mycol = w*16 + lr;

  const unsigned short* Am[2] = {hr, phr};
  const int strA[2] = {256, 128};

  bf16x8 BF[8];
  #pragma unroll
  for (int t = 0; t < 2; ++t){
    #pragma unroll
    for (int q = 0; q < 4; ++q){
      const unsigned short* B = t ? B1 : B0;
      BF[t*4+q] = *(const bf16x8*)(B + (size_t)mycol*CH + q*32 + kq*8);
    }
  }
  float bs = bias[mycol];

  for (int tile = blockIdx.x; tile < NTILES; tile += gridDim.x){
    int r0 = tile * 16;
    int rA = r0 + lr;
    f32x4 acc0 = (f32x4){0.f,0.f,0.f,0.f};
    f32x4 acc1 = (f32x4){0.f,0.f,0.f,0.f};
    #pragma unroll
    for (int q = 0; q < 4; ++q){
      bf16x8 a0 = *(const bf16x8*)(Am[0] + (size_t)rA*256 + q*32 + kq*8);
      bf16x8 a1 = *(const bf16x8*)(Am[1] + (size_t)rA*128 + q*32 + kq*8);
      acc0 = __builtin_amdgcn_mfma_f32_16x16x32_bf16(a0, BF[q],   acc0, 0, 0, 0);
      acc1 = __builtin_amdgcn_mfma_f32_16x16x32_bf16(a1, BF[4+q], acc1, 0, 0, 0);
    }
    #pragma unroll
    for (int j = 0; j < 4; ++j){
      int row = r0 + kq*4 + j;
      size_t o = (size_t)row*CH + mycol;
      float ht = tanhf(acc0[j] + acc1[j] + bs + pre2[o]);
      float z  = bf2f(zb[o]);
      float h  = z*Hp[o] + (1.0f - z)*ht;
      hidden[o] = h;
      relu_b[o] = f2bf(fmaxf(h, 0.0f));
    }
  }
}

// ---------------- link-pred scores: 16-lane group per pair, bf16 rows ---------
__global__ void scores_bf16(const int* __restrict__ eli, const unsigned short* __restrict__ hr,
                            const float* __restrict__ pw, const float* __restrict__ pb,
                            float* __restrict__ out){
  __shared__ float sw[CH];
  int t = threadIdx.x;
  if (t < CH) sw[t] = pw[2*t] + pw[2*t + 1];
  __syncthreads();
  int pair = blockIdx.x*16 + (t >> 4);
  if (pair >= N_EL) return;
  int il = t & 15;
  int a = eli[pair];
  int b = eli[N_EL + pair];
  bf16x8 va = *(const bf16x8*)(hr + (size_t)a*CH + il*8);
  bf16x8 vb = *(const bf16x8*)(hr + (size_t)b*CH + il*8);
  float s = 0.f;
  #pragma unroll
  for (int j = 0; j < 8; ++j){
    s += bf2f((unsigned short)va[j]) * bf2f((unsigned short)vb[j]) * sw[il*8 + j];
  }
  s += __shfl_xor(s, 1, 64);
  s += __shfl_xor(s, 2, 64);
  s += __shfl_xor(s, 4, 64);
  s += __shfl_xor(s, 8, 64);
  if (il == 0) out[pair] = s + pb[0] + pb[1];
}

extern "C" void kernel_launch(void* const* d_in, const int* in_sizes, int n_in,
                              void* d_out, int out_size, void* d_ws, size_t ws_size,
                              hipStream_t stream) {
  const float* x   = (const float*)d_in[0];
  const int*   ei  = (const int*)d_in[1];
  const int*   eli = (const int*)d_in[2];
  const float* H   = (const float*)d_in[3];
  const float* Wx0 = (const float*)d_in[4];
  const float* Wx1 = (const float*)d_in[5];
  const float* bx  = (const float*)d_in[6];
  const float* Wh0 = (const float*)d_in[7];
  const float* Wh1 = (const float*)d_in[8];
  const float* bh  = (const float*)d_in[9];
  const float* pw  = (const float*)d_in[10];
  const float* pb  = (const float*)d_in[11];
  float* out    = (float*)d_out;
  float* scores = out;
  float* hidden = out + N_EL;

  char* w = (char*)d_ws;
  auto alloc = [&](size_t b){ void* p = (void*)w; w += (b + 255) & ~(size_t)255; return p; };
  int*   deg      = (int*)  alloc((size_t)N_NODES*4);
  int*   cnt      = (int*)  alloc((size_t)N_NODES*4);
  float* dinv     = (float*)alloc((size_t)N_NODES*4);
  int*   rowoff   = (int*)  alloc((size_t)(N_NODES+1)*4);
  int*   cursor   = (int*)  alloc((size_t)N_NODES*4);
  int*   bsum     = (int*)  alloc((size_t)SCAN_NB*4);
  int*   boff     = (int*)  alloc((size_t)SCAN_NB*4);
  int*   csr_src  = (int*)  alloc((size_t)N_EDGES*4);
  float* csr_norm = (float*)alloc((size_t)N_EDGES*4);
  unsigned short* wt  = (unsigned short*)alloc((size_t)12*128*128*2);
  unsigned short* xHb = (unsigned short*)alloc((size_t)N_NODES*256*2);  // x|H interleaved
  unsigned short* pxb = (unsigned short*)alloc((size_t)N_NODES*CH*2);
  unsigned short* pHb = (unsigned short*)alloc((size_t)N_NODES*CH*2);
  unsigned short* zbb = (unsigned short*)alloc((size_t)N_NODES*CH*2);
  float* pre2 = (float*)alloc((size_t)N_NODES*CH*4);
  unsigned short* pHRb   = pHb;   // pHb dead after mfma_gates2
  unsigned short* relu_b = pxb;   // pxb dead after mfma_gates2

  hipMemsetAsync(deg, 0, (size_t)N_NODES*4, stream);
  hipMemsetAsync(cnt, 0, (size_t)N_NODES*4, stream);

  hist_kernel<<<(N_EDGES+255)/256, 256, 0, stream>>>(ei, deg, cnt);
  dinv_kernel<<<(N_NODES+255)/256, 256, 0, stream>>>(deg, dinv);
  scan_bsum <<<SCAN_NB, 256, 0, stream>>>(cnt, bsum);
  scan_boff <<<1, 256, 0, stream>>>(bsum, boff);
  scan_final<<<SCAN_NB, 256, 0, stream>>>(cnt, boff, rowoff, cursor);
  scatter_kernel<<<(N_EDGES+255)/256, 256, 0, stream>>>(ei, dinv, cursor, csr_src, csr_norm);

  cvt_xH<<<(((N_NODES*CH)/4)*2 + 255)/256, 256, 0, stream>>>(x, H, xHb);
  cvt_w <<<(12*128*128 + 255)/256, 256, 0, stream>>>(Wx0, Wx1, Wh0, Wh1, wt);

  prop_x2<<<(N_NODES+3)/4, 256, 0, stream>>>(rowoff, csr_src, csr_norm, xHb, pxb, pHb);

  const size_t M = 128*128;
  // fused gates: Z (bf16) + HR (bf16 in-place into xHb H-half) + pre2 (fp32)
  mfma_gates2<<<512, 512, 0, stream>>>(xHb, pxb, pHb, wt, bx, bh, zbb, pre2);
  // pHR = prop(HR)
  prop_one<<<(N_NODES+3)/4, 256, 0, stream>>>(rowoff, csr_src, csr_norm, xHb + 128, pHRb);
  // gate 2 h-part + GRU finalize: hidden (fp32, d_out) + relu (bf16)
  mfma_final2<<<512, 512, 0, stream>>>(xHb + 128, pHRb, wt + 8*M, wt + 11*M,
      bh + 256, H, pre2, zbb, hidden, relu_b);

  scores_bf16<<<(N_EL+15)/16, 256, 0, stream>>>(eli, relu_b, pw, pb, scores);
}